// Round 5
// baseline (902.285 us; speedup 1.0000x reference)
//
#include <hip/hip_runtime.h>

static constexpr int NN = 16384;
static constexpr int NE = 262144;   // 2^18

#define DEV __device__ __forceinline__

// soft_unit_step(x) = x>0 ? exp(-1/x) : 0
DEV float sus(float x) { return x > 0.0f ? __expf(-1.0f / x) : 0.0f; }

// order-preserving uint key for float atomicMax
DEV unsigned fkey(float f) {
    unsigned b = __float_as_uint(f);
    return b ^ ((b >> 31) ? 0xFFFFFFFFu : 0x80000000u);
}
DEV float funkey(unsigned k) {
    unsigned b = (k >> 31) ? (k ^ 0x80000000u) : ~k;
    return __uint_as_float(b);
}

static constexpr float INV_SQRT20 = 0.22360679774997896f;
static constexpr float INV_SQRT8  = 0.35355339059327373f;
static constexpr float INV3       = 0.5773502691896258f;   // 1/sqrt(3)
static constexpr float NORM_TP    = 0.20412414523193154f;  // 1/sqrt(24)
static constexpr float FAN        = 0.11180339887498948f;  // 1/sqrt(80)
static constexpr float SQRT3      = 1.7320508075688772f;
static constexpr float S0C        = INV_SQRT20 * NORM_TP;          // scalar-out scale
static constexpr float S1C        = INV_SQRT20 * NORM_TP * INV3;   // vector-out scale

// ---------------------------------------------------------------------------
// K0: per-node precompute.  qd0[8], qd1[4][3]  (q projected through Wd),
//     self-interaction -> d_out, z=0, gmax=0.
// ---------------------------------------------------------------------------
__global__ __launch_bounds__(256) void node_pre_kernel(
    const float* __restrict__ f_in,
    const float* __restrict__ Wq0, const float* __restrict__ Wq1,
    const float* __restrict__ Wd0, const float* __restrict__ Wd1,
    const float* __restrict__ Ws0, const float* __restrict__ Ws1,
    float* __restrict__ qd, float* __restrict__ z, unsigned* __restrict__ gmax,
    float* __restrict__ out)
{
    int n = blockIdx.x * 256 + threadIdx.x;
    if (n >= NN) return;

    float f0[16], f1[8][3];
#pragma unroll
    for (int i = 0; i < 16; ++i) f0[i] = f_in[n * 40 + i];
#pragma unroll
    for (int i = 0; i < 8; ++i)
#pragma unroll
        for (int c = 0; c < 3; ++c) f1[i][c] = f_in[n * 40 + 16 + i * 3 + c];

    // q0 = f0 @ Wq0 / 4 ;  qd0 = q0 @ Wd0
    float q0[8];
#pragma unroll
    for (int o = 0; o < 8; ++o) {
        float a = 0.f;
#pragma unroll
        for (int i = 0; i < 16; ++i) a += f0[i] * Wq0[i * 8 + o];
        q0[o] = a * 0.25f;
    }
#pragma unroll
    for (int j = 0; j < 8; ++j) {
        float a = 0.f;
#pragma unroll
        for (int o = 0; o < 8; ++o) a += q0[o] * Wd0[o * 8 + j];
        qd[n * 20 + j] = a;
    }
    // q1[o][c] = sum_i f1[i][c] Wq1[i,o] / sqrt(8) ;  qd1 = Wd1^T q1
    float q1[4][3];
#pragma unroll
    for (int o = 0; o < 4; ++o)
#pragma unroll
        for (int c = 0; c < 3; ++c) {
            float a = 0.f;
#pragma unroll
            for (int i = 0; i < 8; ++i) a += f1[i][c] * Wq1[i * 4 + o];
            q1[o][c] = a * INV_SQRT8;
        }
#pragma unroll
    for (int j = 0; j < 4; ++j)
#pragma unroll
        for (int c = 0; c < 3; ++c) {
            float a = 0.f;
#pragma unroll
            for (int o = 0; o < 4; ++o) a += q1[o][c] * Wd1[o * 4 + j];
            qd[n * 20 + 8 + j * 3 + c] = a;
        }

    // self interaction -> out (d_out is poisoned every launch; we own the init)
#pragma unroll
    for (int o = 0; o < 16; ++o) {
        float a = 0.f;
#pragma unroll
        for (int i = 0; i < 16; ++i) a += f0[i] * Ws0[i * 16 + o];
        out[n * 40 + o] = a * 0.25f;
    }
#pragma unroll
    for (int o = 0; o < 8; ++o)
#pragma unroll
        for (int c = 0; c < 3; ++c) {
            float a = 0.f;
#pragma unroll
            for (int i = 0; i < 8; ++i) a += f1[i][c] * Ws1[i * 8 + o];
            out[n * 40 + 16 + o * 3 + c] = a * INV_SQRT8;
        }

    z[n] = 0.0f;
    if (n == 0) *gmax = 0u;
}

// ---------------------------------------------------------------------------
// shared per-edge geometry helper (emb, sh, cutoff) + f gather
// ---------------------------------------------------------------------------
struct EdgeGeom {
    float shx, shy, shz, len, cutoff;
    float emb[20];
};

DEV void edge_geom(const float* __restrict__ pos, int src, int dst, EdgeGeom& g)
{
    float px = pos[dst * 3 + 0] - pos[src * 3 + 0];
    float py = pos[dst * 3 + 1] - pos[src * 3 + 1];
    float pz = pos[dst * 3 + 2] - pos[src * 3 + 2];
    float len = sqrtf(px * px + py * py + pz * pz);
    float inv = SQRT3 / fmaxf(len, 1e-9f);
    g.shx = px * inv; g.shy = py * inv; g.shz = pz * inv;
    g.len = len;
    g.cutoff = sus(10.0f - len);
    const float cemb = (float)(1.14136 * 7.3890560989306495 * 4.47213595499958);
#pragma unroll
    for (int b = 0; b < 20; ++b) {
        float d = (len - (float)(b + 1) * (10.0f / 21.0f)) * 2.1f;
        g.emb[b] = cemb * sus(d + 1.0f) * sus(1.0f - d);
    }
}

// ---------------------------------------------------------------------------
// K1: per-edge K tensor product + attention logit (+ block max -> gmax)
// ---------------------------------------------------------------------------
__global__ __launch_bounds__(256) void edge_k_kernel(
    const float* __restrict__ pos, const float* __restrict__ f_in,
    const int* __restrict__ esrc, const int* __restrict__ edst,
    const float* __restrict__ Wk1, const float* __restrict__ Wk2,
    const float* __restrict__ qd,
    float* __restrict__ logitbuf, float* __restrict__ cutoffbuf,
    unsigned* __restrict__ gmax)
{
    int e = blockIdx.x * 256 + threadIdx.x;
    int src = esrc[e], dst = edst[e];
    EdgeGeom g;
    edge_geom(pos, src, dst, g);
    cutoffbuf[e] = g.cutoff;

    float f0[16], f1[8][3], dv[8];
#pragma unroll
    for (int i = 0; i < 16; ++i) f0[i] = f_in[src * 40 + i];
#pragma unroll
    for (int i = 0; i < 8; ++i) {
        float a = f_in[src * 40 + 16 + i * 3 + 0];
        float b = f_in[src * 40 + 16 + i * 3 + 1];
        float c = f_in[src * 40 + 16 + i * 3 + 2];
        f1[i][0] = a; f1[i][1] = b; f1[i][2] = c;
        dv[i] = (a * g.shx + b * g.shy + c * g.shz) * INV3;
    }

    float k0a[8] = {0}, Aa[4] = {0}, Ba[4][3] = {{0}};
#pragma clang loop unroll(disable)
    for (int h = 0; h < 20; ++h) {
        float a = 0.f;
#pragma unroll
        for (int b = 0; b < 20; ++b) a += g.emb[b] * Wk1[b * 20 + h];
        float hk = fmaxf(a * INV_SQRT20, 0.0f);
        const float* wr = Wk2 + h * 288;
#pragma unroll
        for (int o = 0; o < 8; ++o) {
            float s = 0.f;
#pragma unroll
            for (int i = 0; i < 16; ++i) s += f0[i] * wr[i * 8 + o];
#pragma unroll
            for (int i = 0; i < 8; ++i)  s += dv[i] * wr[128 + i * 8 + o];
            k0a[o] += hk * s;
        }
#pragma unroll
        for (int o = 0; o < 4; ++o) {
            float s = 0.f;
#pragma unroll
            for (int i = 0; i < 16; ++i) s += f0[i] * wr[192 + i * 4 + o];
            Aa[o] += hk * s;
            float s0 = 0.f, s1 = 0.f, s2 = 0.f;
#pragma unroll
            for (int i = 0; i < 8; ++i) {
                float w = wr[256 + i * 4 + o];
                s0 += f1[i][0] * w; s1 += f1[i][1] * w; s2 += f1[i][2] * w;
            }
            Ba[o][0] += hk * s0; Ba[o][1] += hk * s1; Ba[o][2] += hk * s2;
        }
    }

    // logit = fan * ( qd0 . k0  +  inv3 * sum qd1 . k1 )
    float lg = 0.f;
#pragma unroll
    for (int o = 0; o < 8; ++o) lg += qd[dst * 20 + o] * (k0a[o] * S0C);
    float lg1 = 0.f;
#pragma unroll
    for (int o = 0; o < 4; ++o) {
        float k1x = (Aa[o] * g.shx + Ba[o][0]) * S1C;
        float k1y = (Aa[o] * g.shy + Ba[o][1]) * S1C;
        float k1z = (Aa[o] * g.shz + Ba[o][2]) * S1C;
        lg1 += qd[dst * 20 + 8 + o * 3 + 0] * k1x
             + qd[dst * 20 + 8 + o * 3 + 1] * k1y
             + qd[dst * 20 + 8 + o * 3 + 2] * k1z;
    }
    lg = (lg + lg1 * INV3) * FAN;
    logitbuf[e] = lg;

    // block max -> global atomicMax (ordered-uint key)
    float m = lg;
#pragma unroll
    for (int off = 32; off >= 1; off >>= 1) m = fmaxf(m, __shfl_xor(m, off, 64));
    __shared__ float sm[4];
    int lane = threadIdx.x & 63, wid = threadIdx.x >> 6;
    if (lane == 0) sm[wid] = m;
    __syncthreads();
    if (threadIdx.x == 0) {
        float mm = fmaxf(fmaxf(sm[0], sm[1]), fmaxf(sm[2], sm[3]));
        atomicMax(gmax, fkey(mm));
    }
}

// ---------------------------------------------------------------------------
// K2: ex = cutoff * exp(logit - max); z[dst] += ex
// ---------------------------------------------------------------------------
__global__ __launch_bounds__(256) void edge_exp_kernel(
    const int* __restrict__ edst,
    const float* __restrict__ logitbuf, const float* __restrict__ cutoffbuf,
    const unsigned* __restrict__ gmax,
    float* __restrict__ exbuf, float* __restrict__ z)
{
    int e = blockIdx.x * 256 + threadIdx.x;
    float gm = funkey(*gmax);
    float ex = cutoffbuf[e] * __expf(logitbuf[e] - gm);
    exbuf[e] = ex;
    atomicAdd(&z[edst[e]], ex);
}

// ---------------------------------------------------------------------------
// K3 (fused): V tensor product + attention weight + direct scatter into out.
//   w = sqrt(ex/z~ + eps);  out[dst, :] += w * v
// ---------------------------------------------------------------------------
__global__ __launch_bounds__(256) void edge_v_fused_kernel(
    const float* __restrict__ pos, const float* __restrict__ f_in,
    const int* __restrict__ esrc, const int* __restrict__ edst,
    const float* __restrict__ Wv1, const float* __restrict__ Wv2,
    const float* __restrict__ exbuf, const float* __restrict__ z,
    float* __restrict__ out)
{
    int e = blockIdx.x * 256 + threadIdx.x;
    int src = esrc[e], dst = edst[e];
    EdgeGeom g;
    edge_geom(pos, src, dst, g);

    float f0[16], f1[8][3], dv[8];
#pragma unroll
    for (int i = 0; i < 16; ++i) f0[i] = f_in[src * 40 + i];
#pragma unroll
    for (int i = 0; i < 8; ++i) {
        float a = f_in[src * 40 + 16 + i * 3 + 0];
        float b = f_in[src * 40 + 16 + i * 3 + 1];
        float c = f_in[src * 40 + 16 + i * 3 + 2];
        f1[i][0] = a; f1[i][1] = b; f1[i][2] = c;
        dv[i] = (a * g.shx + b * g.shy + c * g.shz) * INV3;
    }

    float v0a[16] = {0}, Aa[8] = {0}, Ba[8][3] = {{0}};
#pragma clang loop unroll(disable)
    for (int h = 0; h < 20; ++h) {
        float a = 0.f;
#pragma unroll
        for (int b = 0; b < 20; ++b) a += g.emb[b] * Wv1[b * 20 + h];
        float hv = fmaxf(a * INV_SQRT20, 0.0f);
        const float* wr = Wv2 + h * 576;
#pragma unroll
        for (int o = 0; o < 16; ++o) {
            float s = 0.f;
#pragma unroll
            for (int i = 0; i < 16; ++i) s += f0[i] * wr[i * 16 + o];
#pragma unroll
            for (int i = 0; i < 8; ++i)  s += dv[i] * wr[256 + i * 16 + o];
            v0a[o] += hv * s;
        }
#pragma unroll
        for (int o = 0; o < 8; ++o) {
            float s = 0.f;
#pragma unroll
            for (int i = 0; i < 16; ++i) s += f0[i] * wr[384 + i * 8 + o];
            Aa[o] += hv * s;
            float s0 = 0.f, s1 = 0.f, s2 = 0.f;
#pragma unroll
            for (int i = 0; i < 8; ++i) {
                float w = wr[512 + i * 8 + o];
                s0 += f1[i][0] * w; s1 += f1[i][1] * w; s2 += f1[i][2] * w;
            }
            Ba[o][0] += hv * s0; Ba[o][1] += hv * s1; Ba[o][2] += hv * s2;
        }
    }

    // attention weight
    float zz = z[dst];
    zz = (zz < 1e-6f) ? 1.0f : zz;
    float w = sqrtf(exbuf[e] / zz + 1e-6f);

    // direct scatter: out[dst, t] += w * v[t]
    float* od = out + (size_t)dst * 40;
#pragma unroll
    for (int o = 0; o < 16; ++o) atomicAdd(&od[o], w * v0a[o] * S0C);
#pragma unroll
    for (int o = 0; o < 8; ++o) {
        atomicAdd(&od[16 + o * 3 + 0], w * (Aa[o] * g.shx + Ba[o][0]) * S1C);
        atomicAdd(&od[16 + o * 3 + 1], w * (Aa[o] * g.shy + Ba[o][1]) * S1C);
        atomicAdd(&od[16 + o * 3 + 2], w * (Aa[o] * g.shz + Ba[o][2]) * S1C);
    }
}

// ---------------------------------------------------------------------------
extern "C" void kernel_launch(void* const* d_in, const int* in_sizes, int n_in,
                              void* d_out, int out_size, void* d_ws, size_t ws_size,
                              hipStream_t stream)
{
    const float* pos  = (const float*)d_in[0];
    const float* f_in = (const float*)d_in[1];
    const int*   esrc = (const int*)d_in[2];
    const int*   edst = (const int*)d_in[3];
    const float* Wq0  = (const float*)d_in[4];
    const float* Wq1  = (const float*)d_in[5];
    const float* Wk1  = (const float*)d_in[6];
    const float* Wk2  = (const float*)d_in[7];
    const float* Wv1  = (const float*)d_in[8];
    const float* Wv2  = (const float*)d_in[9];
    const float* Wd0  = (const float*)d_in[10];
    const float* Wd1  = (const float*)d_in[11];
    const float* Ws0  = (const float*)d_in[12];
    const float* Ws1  = (const float*)d_in[13];
    float* out = (float*)d_out;

    float* ws = (float*)d_ws;
    float* qd     = ws;                    // NN*20
    float* logitb = qd + (size_t)NN * 20;  // NE
    float* cutb   = logitb + NE;           // NE
    float* exb    = cutb + NE;             // NE
    float* z      = exb + NE;              // NN
    unsigned* gmax = (unsigned*)(z + NN);  // 1 (+3 pad)

    node_pre_kernel<<<NN / 256, 256, 0, stream>>>(f_in, Wq0, Wq1, Wd0, Wd1, Ws0, Ws1,
                                                  qd, z, gmax, out);
    edge_k_kernel<<<NE / 256, 256, 0, stream>>>(pos, f_in, esrc, edst, Wk1, Wk2, qd,
                                                logitb, cutb, gmax);
    edge_exp_kernel<<<NE / 256, 256, 0, stream>>>(edst, logitb, cutb, gmax, exb, z);
    edge_v_fused_kernel<<<NE / 256, 256, 0, stream>>>(pos, f_in, esrc, edst, Wv1, Wv2,
                                                      exb, z, out);
}

// Round 7
// 549.831 us; speedup vs baseline: 1.6410x; 1.6410x over previous
//
#include <hip/hip_runtime.h>

static constexpr int NN = 16384;
static constexpr int NE = 262144;   // 2^18

#define DEV __device__ __forceinline__

DEV float sus(float x) { return x > 0.0f ? __expf(-1.0f / x) : 0.0f; }

DEV unsigned fkey(float f) {
    unsigned b = __float_as_uint(f);
    return b ^ ((b >> 31) ? 0xFFFFFFFFu : 0x80000000u);
}
DEV float funkey(unsigned k) {
    unsigned b = (k >> 31) ? (k ^ 0x80000000u) : ~k;
    return __uint_as_float(b);
}

static constexpr float INV_SQRT20 = 0.22360679774997896f;
static constexpr float INV_SQRT8  = 0.35355339059327373f;
static constexpr float INV3       = 0.5773502691896258f;   // 1/sqrt(3)
static constexpr float NORM_TP    = 0.20412414523193154f;  // 1/sqrt(24)
static constexpr float FAN        = 0.11180339887498948f;  // 1/sqrt(80)
static constexpr float SQRT3      = 1.7320508075688772f;
static constexpr float S0C        = INV_SQRT20 * NORM_TP;
static constexpr float S1C        = INV_SQRT20 * NORM_TP * INV3;

struct alignas(16) F40 { float v[40]; };

// ---------------------------------------------------------------------------
// K0: per-node precompute. qd (q through Wd), self-interaction -> out,
//     z=0, cnt=0, gmax=0.
// ---------------------------------------------------------------------------
__global__ __launch_bounds__(256) void node_pre_kernel(
    const float* __restrict__ f_in,
    const float* __restrict__ Wq0, const float* __restrict__ Wq1,
    const float* __restrict__ Wd0, const float* __restrict__ Wd1,
    const float* __restrict__ Ws0, const float* __restrict__ Ws1,
    float* __restrict__ qd, float* __restrict__ z, int* __restrict__ cnt,
    unsigned* __restrict__ gmax, float* __restrict__ out)
{
    int n = blockIdx.x * 256 + threadIdx.x;
    if (n >= NN) return;

    F40 fr = *(const F40*)(f_in + (size_t)n * 40);
    float f0[16], f1[8][3];
#pragma unroll
    for (int i = 0; i < 16; ++i) f0[i] = fr.v[i];
#pragma unroll
    for (int i = 0; i < 8; ++i)
#pragma unroll
        for (int c = 0; c < 3; ++c) f1[i][c] = fr.v[16 + i * 3 + c];

    float q0[8];
#pragma unroll
    for (int o = 0; o < 8; ++o) {
        float a = 0.f;
#pragma unroll
        for (int i = 0; i < 16; ++i) a += f0[i] * Wq0[i * 8 + o];
        q0[o] = a * 0.25f;
    }
#pragma unroll
    for (int j = 0; j < 8; ++j) {
        float a = 0.f;
#pragma unroll
        for (int o = 0; o < 8; ++o) a += q0[o] * Wd0[o * 8 + j];
        qd[n * 20 + j] = a;
    }
    float q1[4][3];
#pragma unroll
    for (int o = 0; o < 4; ++o)
#pragma unroll
        for (int c = 0; c < 3; ++c) {
            float a = 0.f;
#pragma unroll
            for (int i = 0; i < 8; ++i) a += f1[i][c] * Wq1[i * 4 + o];
            q1[o][c] = a * INV_SQRT8;
        }
#pragma unroll
    for (int j = 0; j < 4; ++j)
#pragma unroll
        for (int c = 0; c < 3; ++c) {
            float a = 0.f;
#pragma unroll
            for (int o = 0; o < 4; ++o) a += q1[o][c] * Wd1[o * 4 + j];
            qd[n * 20 + 8 + j * 3 + c] = a;
        }

    // self interaction -> out (we own the init of d_out)
#pragma unroll
    for (int o = 0; o < 16; ++o) {
        float a = 0.f;
#pragma unroll
        for (int i = 0; i < 16; ++i) a += f0[i] * Ws0[i * 16 + o];
        out[(size_t)n * 40 + o] = a * 0.25f;
    }
#pragma unroll
    for (int o = 0; o < 8; ++o)
#pragma unroll
        for (int c = 0; c < 3; ++c) {
            float a = 0.f;
#pragma unroll
            for (int i = 0; i < 8; ++i) a += f1[i][c] * Ws1[i * 8 + o];
            out[(size_t)n * 40 + 16 + o * 3 + c] = a * INV_SQRT8;
        }

    z[n] = 0.0f;
    cnt[n] = 0;
    if (n == 0) *gmax = 0u;
}

// ---------------------------------------------------------------------------
// K1 (merged): geometry + radial MLPs + K-TP (logit, gmax) + V-TP (vws AoS)
//              + dst histogram
// ---------------------------------------------------------------------------
__global__ __launch_bounds__(256) void edge_kv_kernel(
    const float* __restrict__ pos, const float* __restrict__ f_in,
    const int* __restrict__ esrc, const int* __restrict__ edst,
    const float* __restrict__ Wk1, const float* __restrict__ Wk2,
    const float* __restrict__ Wv1, const float* __restrict__ Wv2,
    const float* __restrict__ qd,
    float* __restrict__ logitbuf, float* __restrict__ cutoffbuf,
    float* __restrict__ vws, int* __restrict__ cnt,
    unsigned* __restrict__ gmax)
{
    int e = blockIdx.x * 256 + threadIdx.x;
    int src = esrc[e], dst = edst[e];
    atomicAdd(&cnt[dst], 1);

    // geometry
    float px = pos[dst * 3 + 0] - pos[src * 3 + 0];
    float py = pos[dst * 3 + 1] - pos[src * 3 + 1];
    float pz = pos[dst * 3 + 2] - pos[src * 3 + 2];
    float len = sqrtf(px * px + py * py + pz * pz);
    float inv = SQRT3 / fmaxf(len, 1e-9f);
    float shx = px * inv, shy = py * inv, shz = pz * inv;
    cutoffbuf[e] = sus(10.0f - len);
    float emb[20];
    const float cemb = (float)(1.14136 * 7.3890560989306495 * 4.47213595499958);
#pragma unroll
    for (int b = 0; b < 20; ++b) {
        float d = (len - (float)(b + 1) * (10.0f / 21.0f)) * 2.1f;
        emb[b] = cemb * sus(d + 1.0f) * sus(1.0f - d);
    }

    // f gather (vectorized)
    F40 fr = *(const F40*)(f_in + (size_t)src * 40);
    float f0[16], f1[8][3], dv[8];
#pragma unroll
    for (int i = 0; i < 16; ++i) f0[i] = fr.v[i];
#pragma unroll
    for (int i = 0; i < 8; ++i) {
        float a = fr.v[16 + i * 3 + 0];
        float b = fr.v[16 + i * 3 + 1];
        float c = fr.v[16 + i * 3 + 2];
        f1[i][0] = a; f1[i][1] = b; f1[i][2] = c;
        dv[i] = (a * shx + b * shy + c * shz) * INV3;
    }

    // ---- K phase ----
    {
        float k0a[8] = {0}, Aa[4] = {0}, Ba[4][3] = {{0}};
#pragma clang loop unroll(disable)
        for (int h = 0; h < 20; ++h) {
            float a = 0.f;
#pragma unroll
            for (int b = 0; b < 20; ++b) a += emb[b] * Wk1[b * 20 + h];
            float hk = fmaxf(a * INV_SQRT20, 0.0f);
            const float* wr = Wk2 + h * 288;
#pragma unroll
            for (int o = 0; o < 8; ++o) {
                float s = 0.f;
#pragma unroll
                for (int i = 0; i < 16; ++i) s += f0[i] * wr[i * 8 + o];
#pragma unroll
                for (int i = 0; i < 8; ++i)  s += dv[i] * wr[128 + i * 8 + o];
                k0a[o] += hk * s;
            }
#pragma unroll
            for (int o = 0; o < 4; ++o) {
                float s = 0.f;
#pragma unroll
                for (int i = 0; i < 16; ++i) s += f0[i] * wr[192 + i * 4 + o];
                Aa[o] += hk * s;
                float s0 = 0.f, s1 = 0.f, s2 = 0.f;
#pragma unroll
                for (int i = 0; i < 8; ++i) {
                    float w = wr[256 + i * 4 + o];
                    s0 += f1[i][0] * w; s1 += f1[i][1] * w; s2 += f1[i][2] * w;
                }
                Ba[o][0] += hk * s0; Ba[o][1] += hk * s1; Ba[o][2] += hk * s2;
            }
        }

        const float* qdd = qd + (size_t)dst * 20;
        float lg = 0.f;
#pragma unroll
        for (int o = 0; o < 8; ++o) lg += qdd[o] * (k0a[o] * S0C);
        float lg1 = 0.f;
#pragma unroll
        for (int o = 0; o < 4; ++o) {
            float k1x = (Aa[o] * shx + Ba[o][0]) * S1C;
            float k1y = (Aa[o] * shy + Ba[o][1]) * S1C;
            float k1z = (Aa[o] * shz + Ba[o][2]) * S1C;
            lg1 += qdd[8 + o * 3 + 0] * k1x
                 + qdd[8 + o * 3 + 1] * k1y
                 + qdd[8 + o * 3 + 2] * k1z;
        }
        lg = (lg + lg1 * INV3) * FAN;
        logitbuf[e] = lg;

        float m = lg;
#pragma unroll
        for (int off = 32; off >= 1; off >>= 1) m = fmaxf(m, __shfl_xor(m, off, 64));
        __shared__ float sm[4];
        int lane = threadIdx.x & 63, wid = threadIdx.x >> 6;
        if (lane == 0) sm[wid] = m;
        __syncthreads();
        if (threadIdx.x == 0) {
            float mm = fmaxf(fmaxf(sm[0], sm[1]), fmaxf(sm[2], sm[3]));
            atomicMax(gmax, fkey(mm));
        }
    }

    // ---- V phase ----
    {
        float v0a[16] = {0}, Aa[8] = {0}, Ba[8][3] = {{0}};
#pragma clang loop unroll(disable)
        for (int h = 0; h < 20; ++h) {
            float a = 0.f;
#pragma unroll
            for (int b = 0; b < 20; ++b) a += emb[b] * Wv1[b * 20 + h];
            float hv = fmaxf(a * INV_SQRT20, 0.0f);
            const float* wr = Wv2 + h * 576;
#pragma unroll
            for (int o = 0; o < 16; ++o) {
                float s = 0.f;
#pragma unroll
                for (int i = 0; i < 16; ++i) s += f0[i] * wr[i * 16 + o];
#pragma unroll
                for (int i = 0; i < 8; ++i)  s += dv[i] * wr[256 + i * 16 + o];
                v0a[o] += hv * s;
            }
#pragma unroll
            for (int o = 0; o < 8; ++o) {
                float s = 0.f;
#pragma unroll
                for (int i = 0; i < 16; ++i) s += f0[i] * wr[384 + i * 8 + o];
                Aa[o] += hv * s;
                float s0 = 0.f, s1 = 0.f, s2 = 0.f;
#pragma unroll
                for (int i = 0; i < 8; ++i) {
                    float w = wr[512 + i * 8 + o];
                    s0 += f1[i][0] * w; s1 += f1[i][1] * w; s2 += f1[i][2] * w;
                }
                Ba[o][0] += hv * s0; Ba[o][1] += hv * s1; Ba[o][2] += hv * s2;
            }
        }

        F40 varr;
#pragma unroll
        for (int o = 0; o < 16; ++o) varr.v[o] = v0a[o] * S0C;
#pragma unroll
        for (int o = 0; o < 8; ++o) {
            varr.v[16 + o * 3 + 0] = (Aa[o] * shx + Ba[o][0]) * S1C;
            varr.v[16 + o * 3 + 1] = (Aa[o] * shy + Ba[o][1]) * S1C;
            varr.v[16 + o * 3 + 2] = (Aa[o] * shz + Ba[o][2]) * S1C;
        }
        *(F40*)(vws + (size_t)e * 40) = varr;
    }
}

// ---------------------------------------------------------------------------
// K2: exclusive scan of cnt[NN] -> seg[NN+1], copy to cursor.  1 block, 1024 thr.
// ---------------------------------------------------------------------------
__global__ __launch_bounds__(1024) void scan_kernel(
    const int* __restrict__ cnt, int* __restrict__ seg, int* __restrict__ cursor)
{
    __shared__ int part[1024];
    int tid = threadIdx.x;
    int base = tid * 16;
    int loc[16];
    int s = 0;
#pragma unroll
    for (int i = 0; i < 16; ++i) { loc[i] = s; s += cnt[base + i]; }
    part[tid] = s;
    __syncthreads();
    for (int off = 1; off < 1024; off <<= 1) {
        int add = (tid >= off) ? part[tid - off] : 0;
        __syncthreads();
        part[tid] += add;
        __syncthreads();
    }
    int excl = part[tid] - s;
#pragma unroll
    for (int i = 0; i < 16; ++i) {
        int v = excl + loc[i];
        seg[base + i] = v;
        cursor[base + i] = v;
    }
    if (tid == 1023) seg[NN] = part[1023];
}

// ---------------------------------------------------------------------------
// K3: ex = cutoff * exp(logit - max); z[dst] += ex; build perm (sorted by dst)
// ---------------------------------------------------------------------------
__global__ __launch_bounds__(256) void edge_exp_perm_kernel(
    const int* __restrict__ edst,
    const float* __restrict__ logitbuf, const float* __restrict__ cutoffbuf,
    const unsigned* __restrict__ gmax,
    float* __restrict__ exbuf, float* __restrict__ z,
    int* __restrict__ cursor, int* __restrict__ perm)
{
    int e = blockIdx.x * 256 + threadIdx.x;
    int dst = edst[e];
    float gm = funkey(*gmax);
    float ex = cutoffbuf[e] * __expf(logitbuf[e] - gm);
    exbuf[e] = ex;
    atomicAdd(&z[dst], ex);
    int pos = atomicAdd(&cursor[dst], 1);
    perm[pos] = e;
}

// ---------------------------------------------------------------------------
// K4: atomic-free gather. One wave per dst node; lanes 0..39 = channels.
//     out[dst, t] += sum_{e in dst} sqrt(ex/z~ + eps) * vws[e][t]
// ---------------------------------------------------------------------------
__global__ __launch_bounds__(256) void gather_kernel(
    const int* __restrict__ seg, const int* __restrict__ perm,
    const float* __restrict__ exbuf, const float* __restrict__ z,
    const float* __restrict__ vws, float* __restrict__ out)
{
    int dst = blockIdx.x * 4 + (threadIdx.x >> 6);
    int lane = threadIdx.x & 63;
    if (dst >= NN) return;

    float zz = z[dst];
    zz = (zz < 1e-6f) ? 1.0f : zz;
    float rz = 1.0f / zz;

    if (lane < 40) {
        int s0 = seg[dst], s1 = seg[dst + 1];
        float acc = 0.f;
        for (int j = s0; j < s1; ++j) {
            int eid = perm[j];
            float w = sqrtf(exbuf[eid] * rz + 1e-6f);
            acc += w * vws[(size_t)eid * 40 + lane];
        }
        out[(size_t)dst * 40 + lane] += acc;
    }
}

// ---------------------------------------------------------------------------
extern "C" void kernel_launch(void* const* d_in, const int* in_sizes, int n_in,
                              void* d_out, int out_size, void* d_ws, size_t ws_size,
                              hipStream_t stream)
{
    const float* pos  = (const float*)d_in[0];
    const float* f_in = (const float*)d_in[1];
    const int*   esrc = (const int*)d_in[2];
    const int*   edst = (const int*)d_in[3];
    const float* Wq0  = (const float*)d_in[4];
    const float* Wq1  = (const float*)d_in[5];
    const float* Wk1  = (const float*)d_in[6];
    const float* Wk2  = (const float*)d_in[7];
    const float* Wv1  = (const float*)d_in[8];
    const float* Wv2  = (const float*)d_in[9];
    const float* Wd0  = (const float*)d_in[10];
    const float* Wd1  = (const float*)d_in[11];
    const float* Ws0  = (const float*)d_in[12];
    const float* Ws1  = (const float*)d_in[13];
    float* out = (float*)d_out;

    float* ws = (float*)d_ws;
    float* qd     = ws;                         // NN*20
    float* logitb = qd + (size_t)NN * 20;       // NE
    float* cutb   = logitb + NE;                // NE
    float* exb    = cutb + NE;                  // NE
    float* z      = exb + NE;                   // NN
    unsigned* gmax = (unsigned*)(z + NN);       // 4 (pad)
    int* cnt    = (int*)(gmax + 4);             // NN
    int* seg    = cnt + NN;                     // NN+1 (+pad to NN+8)
    int* cursor = seg + NN + 8;                 // NN
    int* perm   = cursor + NN;                  // NE
    float* vws  = (float*)(perm + NE);          // 40*NE (16B-aligned: offset mult of 4)

    node_pre_kernel<<<NN / 256, 256, 0, stream>>>(f_in, Wq0, Wq1, Wd0, Wd1, Ws0, Ws1,
                                                  qd, z, cnt, gmax, out);
    edge_kv_kernel<<<NE / 256, 256, 0, stream>>>(pos, f_in, esrc, edst, Wk1, Wk2,
                                                 Wv1, Wv2, qd, logitb, cutb, vws,
                                                 cnt, gmax);
    scan_kernel<<<1, 1024, 0, stream>>>(cnt, seg, cursor);
    edge_exp_perm_kernel<<<NE / 256, 256, 0, stream>>>(edst, logitb, cutb, gmax,
                                                       exb, z, cursor, perm);
    gather_kernel<<<NN / 4, 256, 0, stream>>>(seg, perm, exb, z, vws, out);
}

// Round 8
// 440.123 us; speedup vs baseline: 2.0501x; 1.2493x over previous
//
#include <hip/hip_runtime.h>

static constexpr int NN = 16384;
static constexpr int NE = 262144;   // 2^18

#define DEV __device__ __forceinline__

DEV float sus(float x) { return x > 0.0f ? __expf(-1.0f / x) : 0.0f; }

DEV unsigned fkey(float f) {
    unsigned b = __float_as_uint(f);
    return b ^ ((b >> 31) ? 0xFFFFFFFFu : 0x80000000u);
}
DEV float funkey(unsigned k) {
    unsigned b = (k >> 31) ? (k ^ 0x80000000u) : ~k;
    return __uint_as_float(b);
}

static constexpr float INV_SQRT20 = 0.22360679774997896f;
static constexpr float INV_SQRT8  = 0.35355339059327373f;
static constexpr float INV3       = 0.5773502691896258f;   // 1/sqrt(3)
static constexpr float NORM_TP    = 0.20412414523193154f;  // 1/sqrt(24)
static constexpr float FAN        = 0.11180339887498948f;  // 1/sqrt(80)
static constexpr float SQRT3      = 1.7320508075688772f;
static constexpr float S0C        = INV_SQRT20 * NORM_TP;
static constexpr float S1C        = INV_SQRT20 * NORM_TP * INV3;

struct alignas(16) F40 { float v[40]; };

// ---------------------------------------------------------------------------
// K0: per-node precompute. qd (q through Wd), self-interaction -> out,
//     z=0, cnt=0, gmax=0.
// ---------------------------------------------------------------------------
__global__ __launch_bounds__(256) void node_pre_kernel(
    const float* __restrict__ f_in,
    const float* __restrict__ Wq0, const float* __restrict__ Wq1,
    const float* __restrict__ Wd0, const float* __restrict__ Wd1,
    const float* __restrict__ Ws0, const float* __restrict__ Ws1,
    float* __restrict__ qd, float* __restrict__ z, int* __restrict__ cnt,
    unsigned* __restrict__ gmax, float* __restrict__ out)
{
    int n = blockIdx.x * 256 + threadIdx.x;
    if (n >= NN) return;

    F40 fr = *(const F40*)(f_in + (size_t)n * 40);
    float f0[16], f1[8][3];
#pragma unroll
    for (int i = 0; i < 16; ++i) f0[i] = fr.v[i];
#pragma unroll
    for (int i = 0; i < 8; ++i)
#pragma unroll
        for (int c = 0; c < 3; ++c) f1[i][c] = fr.v[16 + i * 3 + c];

    float q0[8];
#pragma unroll
    for (int o = 0; o < 8; ++o) {
        float a = 0.f;
#pragma unroll
        for (int i = 0; i < 16; ++i) a += f0[i] * Wq0[i * 8 + o];
        q0[o] = a * 0.25f;
    }
#pragma unroll
    for (int j = 0; j < 8; ++j) {
        float a = 0.f;
#pragma unroll
        for (int o = 0; o < 8; ++o) a += q0[o] * Wd0[o * 8 + j];
        qd[n * 20 + j] = a;
    }
    float q1[4][3];
#pragma unroll
    for (int o = 0; o < 4; ++o)
#pragma unroll
        for (int c = 0; c < 3; ++c) {
            float a = 0.f;
#pragma unroll
            for (int i = 0; i < 8; ++i) a += f1[i][c] * Wq1[i * 4 + o];
            q1[o][c] = a * INV_SQRT8;
        }
#pragma unroll
    for (int j = 0; j < 4; ++j)
#pragma unroll
        for (int c = 0; c < 3; ++c) {
            float a = 0.f;
#pragma unroll
            for (int o = 0; o < 4; ++o) a += q1[o][c] * Wd1[o * 4 + j];
            qd[n * 20 + 8 + j * 3 + c] = a;
        }

    // self interaction -> out (we own the init of d_out)
#pragma unroll
    for (int o = 0; o < 16; ++o) {
        float a = 0.f;
#pragma unroll
        for (int i = 0; i < 16; ++i) a += f0[i] * Ws0[i * 16 + o];
        out[(size_t)n * 40 + o] = a * 0.25f;
    }
#pragma unroll
    for (int o = 0; o < 8; ++o)
#pragma unroll
        for (int c = 0; c < 3; ++c) {
            float a = 0.f;
#pragma unroll
            for (int i = 0; i < 8; ++i) a += f1[i][c] * Ws1[i * 8 + o];
            out[(size_t)n * 40 + 16 + o * 3 + c] = a * INV_SQRT8;
        }

    z[n] = 0.0f;
    cnt[n] = 0;
    if (n == 0) *gmax = 0u;
}

// ---------------------------------------------------------------------------
// K1: per-edge K tensor product + logit (+ wave max -> gmax) + dst histogram.
//     64-thread blocks: wave-granular occupancy, no LDS/barrier.
// ---------------------------------------------------------------------------
__global__ __launch_bounds__(64) void edge_k_kernel(
    const float* __restrict__ pos, const float* __restrict__ f_in,
    const int* __restrict__ esrc, const int* __restrict__ edst,
    const float* __restrict__ Wk1, const float* __restrict__ Wk2,
    const float* __restrict__ qd,
    float* __restrict__ logitbuf, float* __restrict__ cutoffbuf,
    int* __restrict__ cnt, unsigned* __restrict__ gmax)
{
    int e = blockIdx.x * 64 + threadIdx.x;
    int src = esrc[e], dst = edst[e];
    atomicAdd(&cnt[dst], 1);

    float px = pos[dst * 3 + 0] - pos[src * 3 + 0];
    float py = pos[dst * 3 + 1] - pos[src * 3 + 1];
    float pz = pos[dst * 3 + 2] - pos[src * 3 + 2];
    float len = sqrtf(px * px + py * py + pz * pz);
    float inv = SQRT3 / fmaxf(len, 1e-9f);
    float shx = px * inv, shy = py * inv, shz = pz * inv;
    cutoffbuf[e] = sus(10.0f - len);
    float emb[20];
    const float cemb = (float)(1.14136 * 7.3890560989306495 * 4.47213595499958);
#pragma unroll
    for (int b = 0; b < 20; ++b) {
        float d = (len - (float)(b + 1) * (10.0f / 21.0f)) * 2.1f;
        emb[b] = cemb * sus(d + 1.0f) * sus(1.0f - d);
    }

    F40 fr = *(const F40*)(f_in + (size_t)src * 40);
    float f0[16], f1[8][3], dv[8];
#pragma unroll
    for (int i = 0; i < 16; ++i) f0[i] = fr.v[i];
#pragma unroll
    for (int i = 0; i < 8; ++i) {
        float a = fr.v[16 + i * 3 + 0];
        float b = fr.v[16 + i * 3 + 1];
        float c = fr.v[16 + i * 3 + 2];
        f1[i][0] = a; f1[i][1] = b; f1[i][2] = c;
        dv[i] = (a * shx + b * shy + c * shz) * INV3;
    }

    float k0a[8] = {0}, Aa[4] = {0}, Ba[4][3] = {{0}};
#pragma clang loop unroll(disable)
    for (int h = 0; h < 20; ++h) {
        float a = 0.f;
#pragma unroll
        for (int b = 0; b < 20; ++b) a += emb[b] * Wk1[b * 20 + h];
        float hk = fmaxf(a * INV_SQRT20, 0.0f);
        const float* wr = Wk2 + h * 288;
#pragma unroll
        for (int o = 0; o < 8; ++o) {
            float s = 0.f;
#pragma unroll
            for (int i = 0; i < 16; ++i) s += f0[i] * wr[i * 8 + o];
#pragma unroll
            for (int i = 0; i < 8; ++i)  s += dv[i] * wr[128 + i * 8 + o];
            k0a[o] += hk * s;
        }
#pragma unroll
        for (int o = 0; o < 4; ++o) {
            float s = 0.f;
#pragma unroll
            for (int i = 0; i < 16; ++i) s += f0[i] * wr[192 + i * 4 + o];
            Aa[o] += hk * s;
            float s0 = 0.f, s1 = 0.f, s2 = 0.f;
#pragma unroll
            for (int i = 0; i < 8; ++i) {
                float w = wr[256 + i * 4 + o];
                s0 += f1[i][0] * w; s1 += f1[i][1] * w; s2 += f1[i][2] * w;
            }
            Ba[o][0] += hk * s0; Ba[o][1] += hk * s1; Ba[o][2] += hk * s2;
        }
    }

    const float* qdd = qd + (size_t)dst * 20;
    float lg = 0.f;
#pragma unroll
    for (int o = 0; o < 8; ++o) lg += qdd[o] * (k0a[o] * S0C);
    float lg1 = 0.f;
#pragma unroll
    for (int o = 0; o < 4; ++o) {
        float k1x = (Aa[o] * shx + Ba[o][0]) * S1C;
        float k1y = (Aa[o] * shy + Ba[o][1]) * S1C;
        float k1z = (Aa[o] * shz + Ba[o][2]) * S1C;
        lg1 += qdd[8 + o * 3 + 0] * k1x
             + qdd[8 + o * 3 + 1] * k1y
             + qdd[8 + o * 3 + 2] * k1z;
    }
    lg = (lg + lg1 * INV3) * FAN;
    logitbuf[e] = lg;

    float m = lg;
#pragma unroll
    for (int off = 32; off >= 1; off >>= 1) m = fmaxf(m, __shfl_xor(m, off, 64));
    if (threadIdx.x == 0) atomicMax(gmax, fkey(m));
}

// ---------------------------------------------------------------------------
// K2: exclusive scan of cnt[NN] -> seg[NN+1], copy to cursor.  1 block.
// ---------------------------------------------------------------------------
__global__ __launch_bounds__(1024) void scan_kernel(
    const int* __restrict__ cnt, int* __restrict__ seg, int* __restrict__ cursor)
{
    __shared__ int part[1024];
    int tid = threadIdx.x;
    int base = tid * 16;
    int loc[16];
    int s = 0;
#pragma unroll
    for (int i = 0; i < 16; ++i) { loc[i] = s; s += cnt[base + i]; }
    part[tid] = s;
    __syncthreads();
    for (int off = 1; off < 1024; off <<= 1) {
        int add = (tid >= off) ? part[tid - off] : 0;
        __syncthreads();
        part[tid] += add;
        __syncthreads();
    }
    int excl = part[tid] - s;
#pragma unroll
    for (int i = 0; i < 16; ++i) {
        int v = excl + loc[i];
        seg[base + i] = v;
        cursor[base + i] = v;
    }
    if (tid == 1023) seg[NN] = part[1023];
}

// ---------------------------------------------------------------------------
// K3: ex = cutoff*exp(logit-max); z[dst]+=ex; assign sorted slot:
//     pos_of[e] = pos, exs[pos] = ex.
// ---------------------------------------------------------------------------
__global__ __launch_bounds__(256) void edge_exp_perm_kernel(
    const int* __restrict__ edst,
    const float* __restrict__ logitbuf, const float* __restrict__ cutoffbuf,
    const unsigned* __restrict__ gmax,
    float* __restrict__ exs, float* __restrict__ z,
    int* __restrict__ cursor, int* __restrict__ pos_of)
{
    int e = blockIdx.x * 256 + threadIdx.x;
    int dst = edst[e];
    float gm = funkey(*gmax);
    float ex = cutoffbuf[e] * __expf(logitbuf[e] - gm);
    atomicAdd(&z[dst], ex);
    int pos = atomicAdd(&cursor[dst], 1);
    pos_of[e] = pos;
    exs[pos] = ex;
}

// ---------------------------------------------------------------------------
// K4: per-edge V tensor product -> vws row at SORTED position pos_of[e].
//     64-thread blocks.
// ---------------------------------------------------------------------------
__global__ __launch_bounds__(64) void edge_v_kernel(
    const float* __restrict__ pos, const float* __restrict__ f_in,
    const int* __restrict__ esrc, const int* __restrict__ edst,
    const float* __restrict__ Wv1, const float* __restrict__ Wv2,
    const int* __restrict__ pos_of, float* __restrict__ vws)
{
    int e = blockIdx.x * 64 + threadIdx.x;
    int src = esrc[e], dst = edst[e];

    float px = pos[dst * 3 + 0] - pos[src * 3 + 0];
    float py = pos[dst * 3 + 1] - pos[src * 3 + 1];
    float pz = pos[dst * 3 + 2] - pos[src * 3 + 2];
    float len = sqrtf(px * px + py * py + pz * pz);
    float inv = SQRT3 / fmaxf(len, 1e-9f);
    float shx = px * inv, shy = py * inv, shz = pz * inv;
    float emb[20];
    const float cemb = (float)(1.14136 * 7.3890560989306495 * 4.47213595499958);
#pragma unroll
    for (int b = 0; b < 20; ++b) {
        float d = (len - (float)(b + 1) * (10.0f / 21.0f)) * 2.1f;
        emb[b] = cemb * sus(d + 1.0f) * sus(1.0f - d);
    }

    F40 fr = *(const F40*)(f_in + (size_t)src * 40);
    float f0[16], f1[8][3], dv[8];
#pragma unroll
    for (int i = 0; i < 16; ++i) f0[i] = fr.v[i];
#pragma unroll
    for (int i = 0; i < 8; ++i) {
        float a = fr.v[16 + i * 3 + 0];
        float b = fr.v[16 + i * 3 + 1];
        float c = fr.v[16 + i * 3 + 2];
        f1[i][0] = a; f1[i][1] = b; f1[i][2] = c;
        dv[i] = (a * shx + b * shy + c * shz) * INV3;
    }

    float v0a[16] = {0}, Aa[8] = {0}, Ba[8][3] = {{0}};
#pragma clang loop unroll(disable)
    for (int h = 0; h < 20; ++h) {
        float a = 0.f;
#pragma unroll
        for (int b = 0; b < 20; ++b) a += emb[b] * Wv1[b * 20 + h];
        float hv = fmaxf(a * INV_SQRT20, 0.0f);
        const float* wr = Wv2 + h * 576;
#pragma unroll
        for (int o = 0; o < 16; ++o) {
            float s = 0.f;
#pragma unroll
            for (int i = 0; i < 16; ++i) s += f0[i] * wr[i * 16 + o];
#pragma unroll
            for (int i = 0; i < 8; ++i)  s += dv[i] * wr[256 + i * 16 + o];
            v0a[o] += hv * s;
        }
#pragma unroll
        for (int o = 0; o < 8; ++o) {
            float s = 0.f;
#pragma unroll
            for (int i = 0; i < 16; ++i) s += f0[i] * wr[384 + i * 8 + o];
            Aa[o] += hv * s;
            float s0 = 0.f, s1 = 0.f, s2 = 0.f;
#pragma unroll
            for (int i = 0; i < 8; ++i) {
                float w = wr[512 + i * 8 + o];
                s0 += f1[i][0] * w; s1 += f1[i][1] * w; s2 += f1[i][2] * w;
            }
            Ba[o][0] += hv * s0; Ba[o][1] += hv * s1; Ba[o][2] += hv * s2;
        }
    }

    F40 varr;
#pragma unroll
    for (int o = 0; o < 16; ++o) varr.v[o] = v0a[o] * S0C;
#pragma unroll
    for (int o = 0; o < 8; ++o) {
        varr.v[16 + o * 3 + 0] = (Aa[o] * shx + Ba[o][0]) * S1C;
        varr.v[16 + o * 3 + 1] = (Aa[o] * shy + Ba[o][1]) * S1C;
        varr.v[16 + o * 3 + 2] = (Aa[o] * shz + Ba[o][2]) * S1C;
    }
    int p = pos_of[e];
    *(F40*)(vws + (size_t)p * 40) = varr;
}

// ---------------------------------------------------------------------------
// K5: streaming gather. One wave per dst; lanes 0..39 = channels.
//     All reads sequential (vws/exs sorted by dst); plain += into out.
// ---------------------------------------------------------------------------
__global__ __launch_bounds__(256) void gather_kernel(
    const int* __restrict__ seg,
    const float* __restrict__ exs, const float* __restrict__ z,
    const float* __restrict__ vws, float* __restrict__ out)
{
    int dst = blockIdx.x * 4 + (threadIdx.x >> 6);
    int lane = threadIdx.x & 63;
    if (dst >= NN) return;

    float zz = z[dst];
    zz = (zz < 1e-6f) ? 1.0f : zz;
    float rz = 1.0f / zz;

    if (lane < 40) {
        int s0 = seg[dst], s1 = seg[dst + 1];
        float acc = 0.f;
        for (int j = s0; j < s1; ++j) {
            float w = sqrtf(exs[j] * rz + 1e-6f);
            acc += w * vws[(size_t)j * 40 + lane];
        }
        out[(size_t)dst * 40 + lane] += acc;
    }
}

// ---------------------------------------------------------------------------
extern "C" void kernel_launch(void* const* d_in, const int* in_sizes, int n_in,
                              void* d_out, int out_size, void* d_ws, size_t ws_size,
                              hipStream_t stream)
{
    const float* pos  = (const float*)d_in[0];
    const float* f_in = (const float*)d_in[1];
    const int*   esrc = (const int*)d_in[2];
    const int*   edst = (const int*)d_in[3];
    const float* Wq0  = (const float*)d_in[4];
    const float* Wq1  = (const float*)d_in[5];
    const float* Wk1  = (const float*)d_in[6];
    const float* Wk2  = (const float*)d_in[7];
    const float* Wv1  = (const float*)d_in[8];
    const float* Wv2  = (const float*)d_in[9];
    const float* Wd0  = (const float*)d_in[10];
    const float* Wd1  = (const float*)d_in[11];
    const float* Ws0  = (const float*)d_in[12];
    const float* Ws1  = (const float*)d_in[13];
    float* out = (float*)d_out;

    float* ws = (float*)d_ws;
    float* qd     = ws;                         // NN*20
    float* logitb = qd + (size_t)NN * 20;       // NE
    float* cutb   = logitb + NE;                // NE
    float* exs    = cutb + NE;                  // NE (sorted by dst)
    float* z      = exs + NE;                   // NN
    unsigned* gmax = (unsigned*)(z + NN);       // 4 (pad)
    int* cnt    = (int*)(gmax + 4);             // NN
    int* seg    = cnt + NN;                     // NN+1 (pad to NN+8)
    int* cursor = seg + NN + 8;                 // NN
    int* pos_of = cursor + NN;                  // NE
    float* vws  = (float*)(pos_of + NE);        // 40*NE, sorted by dst (16B aligned)

    node_pre_kernel<<<NN / 256, 256, 0, stream>>>(f_in, Wq0, Wq1, Wd0, Wd1, Ws0, Ws1,
                                                  qd, z, cnt, gmax, out);
    edge_k_kernel<<<NE / 64, 64, 0, stream>>>(pos, f_in, esrc, edst, Wk1, Wk2, qd,
                                              logitb, cutb, cnt, gmax);
    scan_kernel<<<1, 1024, 0, stream>>>(cnt, seg, cursor);
    edge_exp_perm_kernel<<<NE / 256, 256, 0, stream>>>(edst, logitb, cutb, gmax,
                                                       exs, z, cursor, pos_of);
    edge_v_kernel<<<NE / 64, 64, 0, stream>>>(pos, f_in, esrc, edst, Wv1, Wv2,
                                              pos_of, vws);
    gather_kernel<<<NN / 4, 256, 0, stream>>>(seg, exs, z, vws, out);
}

// Round 10
// 430.659 us; speedup vs baseline: 2.0951x; 1.0220x over previous
//
#include <hip/hip_runtime.h>

static constexpr int NN = 16384;
static constexpr int NE = 262144;   // 2^18

#define DEV __device__ __forceinline__

DEV float sus(float x) { return x > 0.0f ? __expf(-1.0f / x) : 0.0f; }

DEV unsigned fkey(float f) {
    unsigned b = __float_as_uint(f);
    return b ^ ((b >> 31) ? 0xFFFFFFFFu : 0x80000000u);
}
DEV float funkey(unsigned k) {
    unsigned b = (k >> 31) ? (k ^ 0x80000000u) : ~k;
    return __uint_as_float(b);
}

static constexpr float INV_SQRT20 = 0.22360679774997896f;
static constexpr float INV_SQRT8  = 0.35355339059327373f;
static constexpr float INV3       = 0.5773502691896258f;   // 1/sqrt(3)
static constexpr float NORM_TP    = 0.20412414523193154f;  // 1/sqrt(24)
static constexpr float FAN        = 0.11180339887498948f;  // 1/sqrt(80)
static constexpr float SQRT3      = 1.7320508075688772f;
static constexpr float S0C        = INV_SQRT20 * NORM_TP;
static constexpr float S1C        = INV_SQRT20 * NORM_TP * INV3;

struct alignas(16) F40 { float v[40]; };

// ---------------------------------------------------------------------------
// K0: per-node precompute. qd (q through Wd), self-interaction -> out,
//     z=0, cnt=0, gmax=0.
// ---------------------------------------------------------------------------
__global__ __launch_bounds__(256) void node_pre_kernel(
    const float* __restrict__ f_in,
    const float* __restrict__ Wq0, const float* __restrict__ Wq1,
    const float* __restrict__ Wd0, const float* __restrict__ Wd1,
    const float* __restrict__ Ws0, const float* __restrict__ Ws1,
    float* __restrict__ qd, float* __restrict__ z, int* __restrict__ cnt,
    unsigned* __restrict__ gmax, float* __restrict__ out)
{
    int n = blockIdx.x * 256 + threadIdx.x;
    if (n >= NN) return;

    F40 fr = *(const F40*)(f_in + (size_t)n * 40);
    float f0[16], f1[8][3];
#pragma unroll
    for (int i = 0; i < 16; ++i) f0[i] = fr.v[i];
#pragma unroll
    for (int i = 0; i < 8; ++i)
#pragma unroll
        for (int c = 0; c < 3; ++c) f1[i][c] = fr.v[16 + i * 3 + c];

    float q0[8];
#pragma unroll
    for (int o = 0; o < 8; ++o) {
        float a = 0.f;
#pragma unroll
        for (int i = 0; i < 16; ++i) a += f0[i] * Wq0[i * 8 + o];
        q0[o] = a * 0.25f;
    }
#pragma unroll
    for (int j = 0; j < 8; ++j) {
        float a = 0.f;
#pragma unroll
        for (int o = 0; o < 8; ++o) a += q0[o] * Wd0[o * 8 + j];
        qd[n * 20 + j] = a;
    }
    float q1[4][3];
#pragma unroll
    for (int o = 0; o < 4; ++o)
#pragma unroll
        for (int c = 0; c < 3; ++c) {
            float a = 0.f;
#pragma unroll
            for (int i = 0; i < 8; ++i) a += f1[i][c] * Wq1[i * 4 + o];
            q1[o][c] = a * INV_SQRT8;
        }
#pragma unroll
    for (int j = 0; j < 4; ++j)
#pragma unroll
        for (int c = 0; c < 3; ++c) {
            float a = 0.f;
#pragma unroll
            for (int o = 0; o < 4; ++o) a += q1[o][c] * Wd1[o * 4 + j];
            qd[n * 20 + 8 + j * 3 + c] = a;
        }

    // self interaction -> out (we own the init of d_out)
#pragma unroll
    for (int o = 0; o < 16; ++o) {
        float a = 0.f;
#pragma unroll
        for (int i = 0; i < 16; ++i) a += f0[i] * Ws0[i * 16 + o];
        out[(size_t)n * 40 + o] = a * 0.25f;
    }
#pragma unroll
    for (int o = 0; o < 8; ++o)
#pragma unroll
        for (int c = 0; c < 3; ++c) {
            float a = 0.f;
#pragma unroll
            for (int i = 0; i < 8; ++i) a += f1[i][c] * Ws1[i * 8 + o];
            out[(size_t)n * 40 + 16 + o * 3 + c] = a * INV_SQRT8;
        }

    z[n] = 0.0f;
    cnt[n] = 0;
    if (n == 0) *gmax = 0u;
}

// ---------------------------------------------------------------------------
// K1: per-edge K tensor product + logit (+ block max -> gmax) + dst histogram.
//     256-thread blocks (measured best: R1 53 µs @ 25% occ, 60% VALU).
// ---------------------------------------------------------------------------
__global__ __launch_bounds__(256) void edge_k_kernel(
    const float* __restrict__ pos, const float* __restrict__ f_in,
    const int* __restrict__ esrc, const int* __restrict__ edst,
    const float* __restrict__ Wk1, const float* __restrict__ Wk2,
    const float* __restrict__ qd,
    float* __restrict__ logitbuf, float* __restrict__ cutoffbuf,
    int* __restrict__ cnt, unsigned* __restrict__ gmax)
{
    int e = blockIdx.x * 256 + threadIdx.x;
    int src = esrc[e], dst = edst[e];
    atomicAdd(&cnt[dst], 1);

    float px = pos[dst * 3 + 0] - pos[src * 3 + 0];
    float py = pos[dst * 3 + 1] - pos[src * 3 + 1];
    float pz = pos[dst * 3 + 2] - pos[src * 3 + 2];
    float len = sqrtf(px * px + py * py + pz * pz);
    float inv = SQRT3 / fmaxf(len, 1e-9f);
    float shx = px * inv, shy = py * inv, shz = pz * inv;
    cutoffbuf[e] = sus(10.0f - len);
    float emb[20];
    const float cemb = (float)(1.14136 * 7.3890560989306495 * 4.47213595499958);
#pragma unroll
    for (int b = 0; b < 20; ++b) {
        float d = (len - (float)(b + 1) * (10.0f / 21.0f)) * 2.1f;
        emb[b] = cemb * sus(d + 1.0f) * sus(1.0f - d);
    }

    F40 fr = *(const F40*)(f_in + (size_t)src * 40);
    float f0[16], f1[8][3], dv[8];
#pragma unroll
    for (int i = 0; i < 16; ++i) f0[i] = fr.v[i];
#pragma unroll
    for (int i = 0; i < 8; ++i) {
        float a = fr.v[16 + i * 3 + 0];
        float b = fr.v[16 + i * 3 + 1];
        float c = fr.v[16 + i * 3 + 2];
        f1[i][0] = a; f1[i][1] = b; f1[i][2] = c;
        dv[i] = (a * shx + b * shy + c * shz) * INV3;
    }

    float k0a[8] = {0}, Aa[4] = {0}, Ba[4][3] = {{0}};
#pragma clang loop unroll(disable)
    for (int h = 0; h < 20; ++h) {
        float a = 0.f;
#pragma unroll
        for (int b = 0; b < 20; ++b) a += emb[b] * Wk1[b * 20 + h];
        float hk = fmaxf(a * INV_SQRT20, 0.0f);
        const float* wr = Wk2 + h * 288;
#pragma unroll
        for (int o = 0; o < 8; ++o) {
            float s = 0.f;
#pragma unroll
            for (int i = 0; i < 16; ++i) s += f0[i] * wr[i * 8 + o];
#pragma unroll
            for (int i = 0; i < 8; ++i)  s += dv[i] * wr[128 + i * 8 + o];
            k0a[o] += hk * s;
        }
#pragma unroll
        for (int o = 0; o < 4; ++o) {
            float s = 0.f;
#pragma unroll
            for (int i = 0; i < 16; ++i) s += f0[i] * wr[192 + i * 4 + o];
            Aa[o] += hk * s;
            float s0 = 0.f, s1 = 0.f, s2 = 0.f;
#pragma unroll
            for (int i = 0; i < 8; ++i) {
                float w = wr[256 + i * 4 + o];
                s0 += f1[i][0] * w; s1 += f1[i][1] * w; s2 += f1[i][2] * w;
            }
            Ba[o][0] += hk * s0; Ba[o][1] += hk * s1; Ba[o][2] += hk * s2;
        }
    }

    const float* qdd = qd + (size_t)dst * 20;
    float lg = 0.f;
#pragma unroll
    for (int o = 0; o < 8; ++o) lg += qdd[o] * (k0a[o] * S0C);
    float lg1 = 0.f;
#pragma unroll
    for (int o = 0; o < 4; ++o) {
        float k1x = (Aa[o] * shx + Ba[o][0]) * S1C;
        float k1y = (Aa[o] * shy + Ba[o][1]) * S1C;
        float k1z = (Aa[o] * shz + Ba[o][2]) * S1C;
        lg1 += qdd[8 + o * 3 + 0] * k1x
             + qdd[8 + o * 3 + 1] * k1y
             + qdd[8 + o * 3 + 2] * k1z;
    }
    lg = (lg + lg1 * INV3) * FAN;
    logitbuf[e] = lg;

    float m = lg;
#pragma unroll
    for (int off = 32; off >= 1; off >>= 1) m = fmaxf(m, __shfl_xor(m, off, 64));
    __shared__ float sm[4];
    int lane = threadIdx.x & 63, wid = threadIdx.x >> 6;
    if (lane == 0) sm[wid] = m;
    __syncthreads();
    if (threadIdx.x == 0) {
        float mm = fmaxf(fmaxf(sm[0], sm[1]), fmaxf(sm[2], sm[3]));
        atomicMax(gmax, fkey(mm));
    }
}

// ---------------------------------------------------------------------------
// K2: exclusive scan of cnt[NN] -> seg[NN+1], copy to cursor.  1 block.
// ---------------------------------------------------------------------------
__global__ __launch_bounds__(1024) void scan_kernel(
    const int* __restrict__ cnt, int* __restrict__ seg, int* __restrict__ cursor)
{
    __shared__ int part[1024];
    int tid = threadIdx.x;
    int base = tid * 16;
    int loc[16];
    int s = 0;
#pragma unroll
    for (int i = 0; i < 16; ++i) { loc[i] = s; s += cnt[base + i]; }
    part[tid] = s;
    __syncthreads();
    for (int off = 1; off < 1024; off <<= 1) {
        int add = (tid >= off) ? part[tid - off] : 0;
        __syncthreads();
        part[tid] += add;
        __syncthreads();
    }
    int excl = part[tid] - s;
#pragma unroll
    for (int i = 0; i < 16; ++i) {
        int v = excl + loc[i];
        seg[base + i] = v;
        cursor[base + i] = v;
    }
    if (tid == 1023) seg[NN] = part[1023];
}

// ---------------------------------------------------------------------------
// K3: ex = cutoff*exp(logit-max); z[dst]+=ex; assign sorted slot:
//     pos_of[e] = pos, exs[pos] = ex.
// ---------------------------------------------------------------------------
__global__ __launch_bounds__(256) void edge_exp_perm_kernel(
    const int* __restrict__ edst,
    const float* __restrict__ logitbuf, const float* __restrict__ cutoffbuf,
    const unsigned* __restrict__ gmax,
    float* __restrict__ exs, float* __restrict__ z,
    int* __restrict__ cursor, int* __restrict__ pos_of)
{
    int e = blockIdx.x * 256 + threadIdx.x;
    int dst = edst[e];
    float gm = funkey(*gmax);
    float ex = cutoffbuf[e] * __expf(logitbuf[e] - gm);
    atomicAdd(&z[dst], ex);
    int pos = atomicAdd(&cursor[dst], 1);
    pos_of[e] = pos;
    exs[pos] = ex;
}

// ---------------------------------------------------------------------------
// K4: per-edge V tensor product -> vws row at SORTED position pos_of[e].
//     256-thread blocks.
// ---------------------------------------------------------------------------
__global__ __launch_bounds__(256) void edge_v_kernel(
    const float* __restrict__ pos, const float* __restrict__ f_in,
    const int* __restrict__ esrc, const int* __restrict__ edst,
    const float* __restrict__ Wv1, const float* __restrict__ Wv2,
    const int* __restrict__ pos_of, float* __restrict__ vws)
{
    int e = blockIdx.x * 256 + threadIdx.x;
    int src = esrc[e], dst = edst[e];

    float px = pos[dst * 3 + 0] - pos[src * 3 + 0];
    float py = pos[dst * 3 + 1] - pos[src * 3 + 1];
    float pz = pos[dst * 3 + 2] - pos[src * 3 + 2];
    float len = sqrtf(px * px + py * py + pz * pz);
    float inv = SQRT3 / fmaxf(len, 1e-9f);
    float shx = px * inv, shy = py * inv, shz = pz * inv;
    float emb[20];
    const float cemb = (float)(1.14136 * 7.3890560989306495 * 4.47213595499958);
#pragma unroll
    for (int b = 0; b < 20; ++b) {
        float d = (len - (float)(b + 1) * (10.0f / 21.0f)) * 2.1f;
        emb[b] = cemb * sus(d + 1.0f) * sus(1.0f - d);
    }

    F40 fr = *(const F40*)(f_in + (size_t)src * 40);
    float f0[16], f1[8][3], dv[8];
#pragma unroll
    for (int i = 0; i < 16; ++i) f0[i] = fr.v[i];
#pragma unroll
    for (int i = 0; i < 8; ++i) {
        float a = fr.v[16 + i * 3 + 0];
        float b = fr.v[16 + i * 3 + 1];
        float c = fr.v[16 + i * 3 + 2];
        f1[i][0] = a; f1[i][1] = b; f1[i][2] = c;
        dv[i] = (a * shx + b * shy + c * shz) * INV3;
    }

    float v0a[16] = {0}, Aa[8] = {0}, Ba[8][3] = {{0}};
#pragma clang loop unroll(disable)
    for (int h = 0; h < 20; ++h) {
        float a = 0.f;
#pragma unroll
        for (int b = 0; b < 20; ++b) a += emb[b] * Wv1[b * 20 + h];
        float hv = fmaxf(a * INV_SQRT20, 0.0f);
        const float* wr = Wv2 + h * 576;
#pragma unroll
        for (int o = 0; o < 16; ++o) {
            float s = 0.f;
#pragma unroll
            for (int i = 0; i < 16; ++i) s += f0[i] * wr[i * 16 + o];
#pragma unroll
            for (int i = 0; i < 8; ++i)  s += dv[i] * wr[256 + i * 16 + o];
            v0a[o] += hv * s;
        }
#pragma unroll
        for (int o = 0; o < 8; ++o) {
            float s = 0.f;
#pragma unroll
            for (int i = 0; i < 16; ++i) s += f0[i] * wr[384 + i * 8 + o];
            Aa[o] += hv * s;
            float s0 = 0.f, s1 = 0.f, s2 = 0.f;
#pragma unroll
            for (int i = 0; i < 8; ++i) {
                float w = wr[512 + i * 8 + o];
                s0 += f1[i][0] * w; s1 += f1[i][1] * w; s2 += f1[i][2] * w;
            }
            Ba[o][0] += hv * s0; Ba[o][1] += hv * s1; Ba[o][2] += hv * s2;
        }
    }

    F40 varr;
#pragma unroll
    for (int o = 0; o < 16; ++o) varr.v[o] = v0a[o] * S0C;
#pragma unroll
    for (int o = 0; o < 8; ++o) {
        varr.v[16 + o * 3 + 0] = (Aa[o] * shx + Ba[o][0]) * S1C;
        varr.v[16 + o * 3 + 1] = (Aa[o] * shy + Ba[o][1]) * S1C;
        varr.v[16 + o * 3 + 2] = (Aa[o] * shz + Ba[o][2]) * S1C;
    }
    int p = pos_of[e];
    *(F40*)(vws + (size_t)p * 40) = varr;
}

// ---------------------------------------------------------------------------
// K5: streaming gather. One wave per dst; lanes 0..39 = channels.
//     All reads sequential (vws/exs sorted by dst); plain += into out.
// ---------------------------------------------------------------------------
__global__ __launch_bounds__(256) void gather_kernel(
    const int* __restrict__ seg,
    const float* __restrict__ exs, const float* __restrict__ z,
    const float* __restrict__ vws, float* __restrict__ out)
{
    int dst = blockIdx.x * 4 + (threadIdx.x >> 6);
    int lane = threadIdx.x & 63;
    if (dst >= NN) return;

    float zz = z[dst];
    zz = (zz < 1e-6f) ? 1.0f : zz;
    float rz = 1.0f / zz;

    if (lane < 40) {
        int s0 = seg[dst], s1 = seg[dst + 1];
        float acc = 0.f;
        for (int j = s0; j < s1; ++j) {
            float w = sqrtf(exs[j] * rz + 1e-6f);
            acc += w * vws[(size_t)j * 40 + lane];
        }
        out[(size_t)dst * 40 + lane] += acc;
    }
}

// ---------------------------------------------------------------------------
extern "C" void kernel_launch(void* const* d_in, const int* in_sizes, int n_in,
                              void* d_out, int out_size, void* d_ws, size_t ws_size,
                              hipStream_t stream)
{
    const float* pos  = (const float*)d_in[0];
    const float* f_in = (const float*)d_in[1];
    const int*   esrc = (const int*)d_in[2];
    const int*   edst = (const int*)d_in[3];
    const float* Wq0  = (const float*)d_in[4];
    const float* Wq1  = (const float*)d_in[5];
    const float* Wk1  = (const float*)d_in[6];
    const float* Wk2  = (const float*)d_in[7];
    const float* Wv1  = (const float*)d_in[8];
    const float* Wv2  = (const float*)d_in[9];
    const float* Wd0  = (const float*)d_in[10];
    const float* Wd1  = (const float*)d_in[11];
    const float* Ws0  = (const float*)d_in[12];
    const float* Ws1  = (const float*)d_in[13];
    float* out = (float*)d_out;

    float* ws = (float*)d_ws;
    float* qd     = ws;                         // NN*20
    float* logitb = qd + (size_t)NN * 20;       // NE
    float* cutb   = logitb + NE;                // NE
    float* exs    = cutb + NE;                  // NE (sorted by dst)
    float* z      = exs + NE;                   // NN
    unsigned* gmax = (unsigned*)(z + NN);       // 4 (pad)
    int* cnt    = (int*)(gmax + 4);             // NN
    int* seg    = cnt + NN;                     // NN+1 (pad to NN+8)
    int* cursor = seg + NN + 8;                 // NN
    int* pos_of = cursor + NN;                  // NE
    float* vws  = (float*)(pos_of + NE);        // 40*NE, sorted by dst (16B aligned)

    node_pre_kernel<<<NN / 256, 256, 0, stream>>>(f_in, Wq0, Wq1, Wd0, Wd1, Ws0, Ws1,
                                                  qd, z, cnt, gmax, out);
    edge_k_kernel<<<NE / 256, 256, 0, stream>>>(pos, f_in, esrc, edst, Wk1, Wk2, qd,
                                                logitb, cutb, cnt, gmax);
    scan_kernel<<<1, 1024, 0, stream>>>(cnt, seg, cursor);
    edge_exp_perm_kernel<<<NE / 256, 256, 0, stream>>>(edst, logitb, cutb, gmax,
                                                       exs, z, cursor, pos_of);
    edge_v_kernel<<<NE / 256, 256, 0, stream>>>(pos, f_in, esrc, edst, Wv1, Wv2,
                                                pos_of, vws);
    gather_kernel<<<NN / 4, 256, 0, stream>>>(seg, exs, z, vws, out);
}